// Round 1
// baseline (186.537 us; speedup 1.0000x reference)
//
#include <hip/hip_runtime.h>
#include <cstdint>

#define NB 8
#define TS 2048
#define NE 1024
#define HD 64
#define MTOT (NB*TS)

typedef float f4  __attribute__((ext_vector_type(4)));
typedef short s8v __attribute__((ext_vector_type(8)));
typedef short s4v __attribute__((ext_vector_type(4)));

__device__ __forceinline__ short f2bf(float f) {
  union { float f; uint32_t u; } x; x.f = f;
  uint32_t r = (x.u + 0x7FFFu + ((x.u >> 16) & 1u)) >> 16;  // RNE
  return (short)r;
}

// ---------------- kernel 1: qkv projection via bf16 MFMA ----------------
// grid (MTOT/128, 3), block 256. blockIdx.y: 0->q (scaled by 0.125*log2e), 1->k, 2->v (stored transposed)
__global__ __launch_bounds__(256) void proj_kernel(
    const float* __restrict__ x, const float* __restrict__ Wk,
    const float* __restrict__ Wq, const float* __restrict__ Wv,
    short* __restrict__ qo, short* __restrict__ ko, short* __restrict__ vo)
{
  __shared__ short xs[128][72];   // stride 72 bf16 = 144 B: 16B-aligned rows, bank-spread
  __shared__ short wsh[64][72];
  const int tid  = threadIdx.x;
  const int wv   = tid >> 6;
  const int lane = tid & 63;
  const int n    = lane & 15;
  const int quad = lane >> 4;
  const int m0   = blockIdx.x * 128;
  const int p    = blockIdx.y;
  const float* W = (p == 0) ? Wq : (p == 1) ? Wk : Wv;

  const f4 fz = {0.f, 0.f, 0.f, 0.f};
  f4 acc[2][4];
#pragma unroll
  for (int a = 0; a < 2; a++)
#pragma unroll
    for (int b = 0; b < 4; b++) acc[a][b] = fz;

  const int lr = tid >> 2;         // 0..63
  const int lc = (tid & 3) * 16;   // 0,16,32,48

  for (int k0 = 0; k0 < NE; k0 += 64) {
    // stage x tile: 128 rows x 64 cols, fp32 -> bf16
#pragma unroll
    for (int rr = 0; rr < 2; rr++) {
      const int row = rr * 64 + lr;
#pragma unroll
      for (int u = 0; u < 4; u++) {
        const float4 v = *(const float4*)&x[(size_t)(m0 + row) * NE + k0 + lc + 4*u];
        s4v h; h[0] = f2bf(v.x); h[1] = f2bf(v.y); h[2] = f2bf(v.z); h[3] = f2bf(v.w);
        *(s4v*)&xs[row][lc + 4*u] = h;
      }
    }
    // stage W tile: 64 x 64
#pragma unroll
    for (int u = 0; u < 4; u++) {
      const float4 v = *(const float4*)&W[(size_t)lr * NE + k0 + lc + 4*u];
      s4v h; h[0] = f2bf(v.x); h[1] = f2bf(v.y); h[2] = f2bf(v.z); h[3] = f2bf(v.w);
      *(s4v*)&wsh[lr][lc + 4*u] = h;
    }
    __syncthreads();

    // wave wv computes rows [wv*32, wv*32+32) x all 64 cols
    s8v af[2][2], bfr[4][2];
#pragma unroll
    for (int mi = 0; mi < 2; mi++)
#pragma unroll
      for (int kc = 0; kc < 2; kc++)
        af[mi][kc] = *(const s8v*)&xs[wv*32 + mi*16 + n][kc*32 + quad*8];
#pragma unroll
    for (int nf = 0; nf < 4; nf++)
#pragma unroll
      for (int kc = 0; kc < 2; kc++)
        bfr[nf][kc] = *(const s8v*)&wsh[nf*16 + n][kc*32 + quad*8];
#pragma unroll
    for (int mi = 0; mi < 2; mi++)
#pragma unroll
      for (int nf = 0; nf < 4; nf++) {
        acc[mi][nf] = __builtin_amdgcn_mfma_f32_16x16x32_bf16(af[mi][0], bfr[nf][0], acc[mi][nf], 0, 0, 0);
        acc[mi][nf] = __builtin_amdgcn_mfma_f32_16x16x32_bf16(af[mi][1], bfr[nf][1], acc[mi][nf], 0, 0, 0);
      }
    __syncthreads();
  }

  // epilogue: C/D layout col=lane&15 (+16*nf), row=quad*4+i (+16*mi +32*wv)
  const float scale = (p == 0) ? 0.18033688011112042f : 1.0f; // q: (1/8)*log2(e) -> exp2-domain softmax
#pragma unroll
  for (int mi = 0; mi < 2; mi++)
#pragma unroll
    for (int nf = 0; nf < 4; nf++)
#pragma unroll
      for (int i = 0; i < 4; i++) {
        const int row = m0 + wv*32 + mi*16 + quad*4 + i;
        const int col = nf*16 + n;
        const short hv = f2bf(acc[mi][nf][i] * scale);
        if (p == 0)      qo[(size_t)row * HD + col] = hv;
        else if (p == 1) ko[(size_t)row * HD + col] = hv;
        else {           // v transposed: [b][d][t] so PV B-frags are contiguous
          const int bb = row >> 11, tt = row & (TS - 1);
          vo[(size_t)bb * HD * TS + (size_t)col * TS + tt] = hv;
        }
      }
}

// ---------------- kernel 2: flash attention, 16 queries/block, 4-way key split ----------------
// grid (MTOT/16), block 256 (4 waves). Wave wv handles keys [wv*512, wv*512+512).
__global__ __launch_bounds__(256) void attn_kernel(
    const short* __restrict__ q, const short* __restrict__ k,
    const short* __restrict__ vT, float* __restrict__ out)
{
  __shared__ short p_s[4][16][72];  // per-wave P transpose buffer (C-layout -> A-layout)
  __shared__ float o_w[4][16][64];  // per-wave partial O for combine
  __shared__ float m_c[4][16];
  __shared__ float l_c[4][16];

  const int tid  = threadIdx.x;
  const int wv   = tid >> 6;
  const int lane = tid & 63;
  const int n    = lane & 15;
  const int quad = lane >> 4;
  const int m0   = blockIdx.x * 16;
  const int bq   = m0 >> 11;       // batch index (2048 rows per batch)

  const f4 fz = {0.f, 0.f, 0.f, 0.f};

  // persistent Q A-frags (q already scaled by 0.125*log2e)
  s8v qf[2];
#pragma unroll
  for (int kc = 0; kc < 2; kc++)
    qf[kc] = *(const s8v*)&q[(size_t)(m0 + n) * HD + kc*32 + quad*8];

  const short* kb = k  + (size_t)bq * TS * HD;
  const short* vb = vT + (size_t)bq * HD * TS;

  f4 o[4];
#pragma unroll
  for (int nf = 0; nf < 4; nf++) o[nf] = fz;
  float m_i[4] = {-1e30f, -1e30f, -1e30f, -1e30f};
  float l_i[4] = {0.f, 0.f, 0.f, 0.f};

  for (int c0 = wv * 512; c0 < wv * 512 + 512; c0 += 64) {
    // K B-frags straight from L2: lane(n,quad) reads K[c0+16f+n][quad*8..+7]
    s8v kf[4][2];
#pragma unroll
    for (int f = 0; f < 4; f++)
#pragma unroll
      for (int kc = 0; kc < 2; kc++)
        kf[f][kc] = *(const s8v*)&kb[(size_t)(c0 + f*16 + n) * HD + kc*32 + quad*8];

    // S = Q K^T (16 queries x 64 keys), C-layout: col=key(n), row=query(quad*4+i)
    f4 s[4];
#pragma unroll
    for (int f = 0; f < 4; f++) {
      s[f] = __builtin_amdgcn_mfma_f32_16x16x32_bf16(qf[0], kf[f][0], fz,   0, 0, 0);
      s[f] = __builtin_amdgcn_mfma_f32_16x16x32_bf16(qf[1], kf[f][1], s[f], 0, 0, 0);
    }

    // online softmax (exp2 domain); row-reduce across the 16 col-lanes via shfl_xor
    float mnew[4], alpha[4], rs[4], pv[4][4];
#pragma unroll
    for (int i = 0; i < 4; i++) {
      float mm = fmaxf(fmaxf(s[0][i], s[1][i]), fmaxf(s[2][i], s[3][i]));
      mm = fmaxf(mm, __shfl_xor(mm, 1));
      mm = fmaxf(mm, __shfl_xor(mm, 2));
      mm = fmaxf(mm, __shfl_xor(mm, 4));
      mm = fmaxf(mm, __shfl_xor(mm, 8));
      mnew[i]  = fmaxf(m_i[i], mm);
      alpha[i] = exp2f(m_i[i] - mnew[i]);
      rs[i] = 0.f;
#pragma unroll
      for (int f = 0; f < 4; f++) { pv[f][i] = exp2f(s[f][i] - mnew[i]); rs[i] += pv[f][i]; }
      rs[i] += __shfl_xor(rs[i], 1);
      rs[i] += __shfl_xor(rs[i], 2);
      rs[i] += __shfl_xor(rs[i], 4);
      rs[i] += __shfl_xor(rs[i], 8);
      l_i[i] = l_i[i] * alpha[i] + rs[i];
      m_i[i] = mnew[i];
    }
#pragma unroll
    for (int nf = 0; nf < 4; nf++)
#pragma unroll
      for (int i = 0; i < 4; i++) o[nf][i] *= alpha[i];

    // P: C-layout -> LDS -> A-layout (per-wave region, wave-internal ordering only)
#pragma unroll
    for (int f = 0; f < 4; f++)
#pragma unroll
      for (int i = 0; i < 4; i++)
        p_s[wv][quad*4 + i][f*16 + n] = f2bf(pv[f][i]);

    asm volatile("s_waitcnt lgkmcnt(0)" ::: "memory");

    s8v pa[2];
#pragma unroll
    for (int kc = 0; kc < 2; kc++)
      pa[kc] = *(const s8v*)&p_s[wv][n][kc*32 + quad*8];
    asm volatile("" ::: "memory");

    // O += P V : B-frags from transposed V (contiguous 8 keys per lane)
#pragma unroll
    for (int nf = 0; nf < 4; nf++) {
      const s8v v0 = *(const s8v*)&vb[(size_t)(nf*16 + n) * TS + c0 + quad*8];
      const s8v v1 = *(const s8v*)&vb[(size_t)(nf*16 + n) * TS + c0 + 32 + quad*8];
      o[nf] = __builtin_amdgcn_mfma_f32_16x16x32_bf16(pa[0], v0, o[nf], 0, 0, 0);
      o[nf] = __builtin_amdgcn_mfma_f32_16x16x32_bf16(pa[1], v1, o[nf], 0, 0, 0);
    }
  }

  // ---- combine 4 key-splits ----
  if (n == 0) {
#pragma unroll
    for (int i = 0; i < 4; i++) {
      m_c[wv][quad*4 + i] = m_i[i];
      l_c[wv][quad*4 + i] = l_i[i];
    }
  }
  __syncthreads();

#pragma unroll
  for (int i = 0; i < 4; i++) {
    const int r = quad*4 + i;
    const float Mx = fmaxf(fmaxf(m_c[0][r], m_c[1][r]), fmaxf(m_c[2][r], m_c[3][r]));
    const float fac = exp2f(m_i[i] - Mx);
#pragma unroll
    for (int nf = 0; nf < 4; nf++)
      o_w[wv][r][nf*16 + n] = o[nf][i] * fac;
  }
  __syncthreads();

  // final: 256 threads write 16x64 fp32 outputs, coalesced float4
  const int r  = tid >> 4;
  const int c4 = (tid & 15) * 4;
  const float Mx = fmaxf(fmaxf(m_c[0][r], m_c[1][r]), fmaxf(m_c[2][r], m_c[3][r]));
  float L = 0.f;
#pragma unroll
  for (int w2 = 0; w2 < 4; w2++) L += l_c[w2][r] * exp2f(m_c[w2][r] - Mx);
  f4 sum = fz;
#pragma unroll
  for (int w2 = 0; w2 < 4; w2++) sum += *(const f4*)&o_w[w2][r][c4];
  sum *= (1.0f / L);
  *(f4*)&out[(size_t)(m0 + r) * HD + c4] = sum;
}

extern "C" void kernel_launch(void* const* d_in, const int* in_sizes, int n_in,
                              void* d_out, int out_size, void* d_ws, size_t ws_size,
                              hipStream_t stream) {
  const float* x  = (const float*)d_in[0];
  const float* Wk = (const float*)d_in[1];
  const float* Wq = (const float*)d_in[2];
  const float* Wv = (const float*)d_in[3];
  float* out = (float*)d_out;

  short* qb = (short*)d_ws;                    // [MTOT][64] bf16, pre-scaled
  short* kb = qb + (size_t)MTOT * HD;          // [MTOT][64] bf16
  short* vb = kb + (size_t)MTOT * HD;          // [NB][64][TS] bf16 (transposed)

  proj_kernel<<<dim3(MTOT/128, 3), 256, 0, stream>>>(x, Wk, Wq, Wv, qb, kb, vb);
  attn_kernel<<<dim3(MTOT/16), 256, 0, stream>>>(qb, kb, vb, out);
}